// Round 6
// baseline (457.237 us; speedup 1.0000x reference)
//
#include <hip/hip_runtime.h>

// SelfAttention (SAGAN-style), MI355X gfx950.
// proj (f16 MFMA GEMM) -> flash attn (32x32x16 swapped-operand, staggered
// producer/consumer pipeline, one barrier/slot) -> combine.
//
// ws layout (~64.5 MB):
//   qw  f16 [4][4096][256]    8 MB  (Q rows)
//   kw  f16 [4][4096][256]    8 MB  (K rows)
//   vw  f16 [4][512][4096]   16 MB  (V, c-major)
//   op  f16 [2][4][512][4096] 32 MB (unnormalized O^T partials, c-major)
//   st  f32 [2][4][4096][2]  0.5 MB (m, l per row per j-half)

#define NPIX 4096
#define CIN  512

typedef _Float16 f16x4 __attribute__((ext_vector_type(4)));
typedef _Float16 f16x8 __attribute__((ext_vector_type(8)));
typedef float    f32x4 __attribute__((ext_vector_type(4)));
typedef float    f32x16 __attribute__((ext_vector_type(16)));

#define MFMA16(a, b, c) __builtin_amdgcn_mfma_f32_16x16x16f16(a, b, c, 0, 0, 0)
#define MFMA32(a, b, c) __builtin_amdgcn_mfma_f32_32x32x16_f16(a, b, c, 0, 0, 0)

__device__ __forceinline__ void gld_lds16(const void* g, void* l) {
    __builtin_amdgcn_global_load_lds(
        (const __attribute__((address_space(1))) unsigned int*)g,
        (__attribute__((address_space(3))) unsigned int*)l, 16, 0, 0);
}

// PV: O^T[c][i] += V[c][j] * P^T[j][i]; slot pairing HW-verified (R3/R4).
template<int NCT, int CB>
__device__ __forceinline__ void pv_step(f32x16* oacc, const char* vb,
                                        int li, int g, f16x8 pa0, f16x8 pa1) {
    #pragma unroll
    for (int ct = 0; ct < NCT; ++ct) {
        const int c = CB + ct * 32 + li;
        const char* vr = vb + c * 72;
        f16x8 va, vc;
        *(f16x4*)&va       = *(const f16x4*)(vr + 8 * g);
        *((f16x4*)&va + 1) = *(const f16x4*)(vr + 16 + 8 * g);
        oacc[ct] = MFMA32(va, pa0, oacc[ct]);
        *(f16x4*)&vc       = *(const f16x4*)(vr + 32 + 8 * g);
        *((f16x4*)&vc + 1) = *(const f16x4*)(vr + 48 + 8 * g);
        oacc[ct] = MFMA32(vc, pa1, oacc[ct]);
    }
}

template<int N>
__device__ __forceinline__ void rescale_acc(f32x16* o, float sc) {
    #pragma unroll
    for (int ct = 0; ct < N; ++ct)
        #pragma unroll
        for (int e = 0; e < 16; ++e) o[ct][e] *= sc;
}

// ---------------------------------------------------------------------------
// Projection: out[o][n], o<256->Q, <512->K, else->V.
// ---------------------------------------------------------------------------
__global__ __launch_bounds__(256) void proj_kernel(
    const float* __restrict__ x,
    const float* __restrict__ f_w, const float* __restrict__ f_b,
    const float* __restrict__ g_w, const float* __restrict__ g_b,
    const float* __restrict__ h_w, const float* __restrict__ h_b,
    _Float16* __restrict__ qw, _Float16* __restrict__ kw,
    _Float16* __restrict__ vw)
{
    const int b  = blockIdx.z;
    const int n0 = blockIdx.x * 64;
    const int o0 = blockIdx.y * 64;

    const float* wsrc; const float* bsrc;
    if (o0 < 256)      { wsrc = f_w + (size_t)o0 * CIN;         bsrc = f_b + o0; }
    else if (o0 < 512) { wsrc = g_w + (size_t)(o0 - 256) * CIN; bsrc = g_b + (o0 - 256); }
    else               { wsrc = h_w + (size_t)(o0 - 512) * CIN; bsrc = h_b + (o0 - 512); }

    __shared__ _Float16 Wt[64][40];
    __shared__ _Float16 Xt[64][40];

    const int t = threadIdx.x;
    const int lane = t & 63, wv = t >> 6;
    const int wm = wv >> 1, wn = wv & 1;
    const int gi = lane >> 4, li = lane & 15;

    f32x4 acc[2][2];
    #pragma unroll
    for (int i = 0; i < 2; ++i)
        #pragma unroll
        for (int j = 0; j < 2; ++j) acc[i][j] = f32x4{0.f, 0.f, 0.f, 0.f};

    for (int kk = 0; kk < CIN; kk += 32) {
        {   // W tile 64x32: one b128 store per thread
            const int r = t >> 2, c8 = (t & 3) * 8;
            const float* p = wsrc + (size_t)r * CIN + kk + c8;
            const float4 v0 = *(const float4*)p;
            const float4 v1 = *(const float4*)(p + 4);
            f16x8 w8;
            w8[0] = (_Float16)v0.x; w8[1] = (_Float16)v0.y;
            w8[2] = (_Float16)v0.z; w8[3] = (_Float16)v0.w;
            w8[4] = (_Float16)v1.x; w8[5] = (_Float16)v1.y;
            w8[6] = (_Float16)v1.z; w8[7] = (_Float16)v1.w;
            *(f16x8*)&Wt[r][c8] = w8;
        }
        {   // X tile 32c x 64n: 8 coalesced dword loads, 1 b128 store
            const int cb = (t >> 6) * 8;
            const int nl = t & 63;
            f16x8 xv;
            #pragma unroll
            for (int e = 0; e < 8; ++e)
                xv[e] = (_Float16)x[((size_t)b * CIN + kk + cb + e) * NPIX +
                                    n0 + nl];
            *(f16x8*)&Xt[nl][cb] = xv;
        }
        __syncthreads();
        #pragma unroll
        for (int kh = 0; kh < 2; ++kh) {
            const int ko = kh * 16 + gi * 4;
            f16x4 a0 = *(const f16x4*)&Wt[wm * 32 +      li][ko];
            f16x4 a1 = *(const f16x4*)&Wt[wm * 32 + 16 + li][ko];
            f16x4 b0 = *(const f16x4*)&Xt[wn * 32 +      li][ko];
            f16x4 b1 = *(const f16x4*)&Xt[wn * 32 + 16 + li][ko];
            acc[0][0] = MFMA16(a0, b0, acc[0][0]);
            acc[0][1] = MFMA16(a0, b1, acc[0][1]);
            acc[1][0] = MFMA16(a1, b0, acc[1][0]);
            acc[1][1] = MFMA16(a1, b1, acc[1][1]);
        }
        __syncthreads();
    }

    #pragma unroll
    for (int mf = 0; mf < 2; ++mf)
        #pragma unroll
        for (int nf = 0; nf < 2; ++nf) {
            const int obase = o0 + wm * 32 + mf * 16 + gi * 4;
            const int n     = n0 + wn * 32 + nf * 16 + li;
            const int brel  = wm * 32 + mf * 16 + gi * 4;
            float v[4];
            #pragma unroll
            for (int r = 0; r < 4; ++r) v[r] = acc[mf][nf][r] + bsrc[brel + r];
            if (o0 < 512) {
                _Float16* dst = (o0 < 256) ? qw : kw;
                const int kb  = (o0 < 256) ? obase : (obase - 256);
                f16x4 pk;
                pk[0] = (_Float16)v[0]; pk[1] = (_Float16)v[1];
                pk[2] = (_Float16)v[2]; pk[3] = (_Float16)v[3];
                *(f16x4*)&dst[((size_t)b * NPIX + n) * 256 + kb] = pk;
            } else {
                #pragma unroll
                for (int r = 0; r < 4; ++r)
                    vw[((size_t)b * CIN + (obase - 512 + r)) * NPIX + n] =
                        (_Float16)v[r];
            }
        }
}

// ---------------------------------------------------------------------------
// Flash attention, one j-half (2048 keys), staggered pipeline.
// 8 waves = 4 row-groups x {producer ch0 (c 0..191), consumer ch1 (c 192..511)}.
// ch = wv>>2 so each SIMD hosts one producer + one consumer.
// Slot s: writeV(s) | stage(s+1) | ch0: QK(s)+SM(s)+publish P(s), then
// apply own P(s-1) | ch1: read P(s-1), PV(s-1). One barrier per slot.
// ---------------------------------------------------------------------------
__global__ __launch_bounds__(512, 2) void attn_kernel(
    const _Float16* __restrict__ qw, const _Float16* __restrict__ kw,
    const _Float16* __restrict__ vw,
    _Float16* __restrict__ opart, float* __restrict__ stats)
{
    const int bid = blockIdx.x;
    const int xcd = bid & 7;
    const int jh = xcd & 1, b = xcd >> 1;
    const int rb = bid >> 3;
    const int t = threadIdx.x, l = t & 63, wv = t >> 6;
    const int li = l & 31, g = l >> 5;
    const int ch = wv >> 2, rg = wv & 3;
    const int i_row = rb * 128 + rg * 32 + li;

    __shared__ char Kt[2][16384];        // 32 rows x 512B, XOR-swizzled
    __shared__ char Vt[2][512 * 72];     // 512 rows x 64B data + 8B pad
    __shared__ char Pt[2][4][64 * 48];   // per lane: pa0(16) pa1(16) sc(4)

    // Q fragments (producers only)
    f16x8 qf[16];
    if (ch == 0) {
        const _Float16* qb = qw + ((size_t)b * NPIX + i_row) * 256 + 8 * g;
        #pragma unroll
        for (int ks = 0; ks < 16; ++ks) qf[ks] = *(const f16x8*)(qb + ks * 16);
    }

    f32x16 oacc[10];   // ch0 uses [0..5] (c 0..191); ch1 uses [0..9] (c 192..511)
    #pragma unroll
    for (int i = 0; i < 10; ++i)
        #pragma unroll
        for (int e = 0; e < 16; ++e) oacc[i][e] = 0.f;
    float m_run = -__builtin_inff();
    float l_run = 0.f;

    f16x8 vreg[4];
    f16x8 paA, paB;           // producer's held-back P(s-1)
    float sc_prev = 1.0f;
    #pragma unroll
    for (int e = 0; e < 8; ++e) { paA[e] = (_Float16)0; paB[e] = (_Float16)0; }

    auto stageK = [&](int buf, int j0) {
        #pragma unroll
        for (int q = 0; q < 2; ++q) {
            const int slot = q * 512 + t;
            const int row  = slot >> 5;
            const int colb = (slot & 31) * 16;
            const char* src =
                (const char*)(kw + ((size_t)b * NPIX + j0 + row) * 256) +
                (colb ^ ((row & 31) << 4));
            gld_lds16(src, Kt[buf] + slot * 16);
        }
    };
    auto loadV = [&](int j0) {
        #pragma unroll
        for (int q = 0; q < 4; ++q) {
            const int c  = q * 128 + (t >> 2);
            const int jj = (t & 3) * 8;
            vreg[q] = *(const f16x8*)(vw + ((size_t)b * CIN + c) * NPIX + j0 + jj);
        }
    };
    auto writeV = [&](int buf) {
        #pragma unroll
        for (int q = 0; q < 4; ++q) {
            const int c = q * 128 + (t >> 2);
            char* d = Vt[buf] + c * 72 + (t & 3) * 16;
            *(f16x4*)d       = *(f16x4*)&vreg[q];
            *(f16x4*)(d + 8) = *((f16x4*)&vreg[q] + 1);
        }
    };

    const int jbase = jh * 2048;
    loadV(jbase);
    stageK(0, jbase);
    if (ch == 0) {   // init Pt[1] (read by consumers at s=0... guarded, but keep sane)
        char* pd = Pt[1][rg] + l * 48;
        *(f16x8*)pd        = paA;
        *(f16x8*)(pd + 16) = paB;
        *(float*)(pd + 32) = 1.0f;
    }
    __syncthreads();

    for (int s = 0; s < 64; ++s) {
        const int cur = s & 1;
        writeV(cur);                       // tile s -> Vt[cur]
        if (s < 63) {
            stageK(cur ^ 1, jbase + (s + 1) * 32);
            loadV(jbase + (s + 1) * 32);
        }

        if (ch == 0) {
            // QK^T: S^T[j][i]; A = K row j=li, B = Q col i=li.
            f32x16 sv;
            #pragma unroll
            for (int e = 0; e < 16; ++e) sv[e] = 0.f;
            {
                const char* kr = Kt[cur] + li * 512;
                const int sw = li << 4;
                __builtin_amdgcn_s_setprio(1);
                #pragma unroll
                for (int ks = 0; ks < 16; ++ks) {
                    f16x8 kf = *(const f16x8*)(kr + ((ks * 32 + 16 * g) ^ sw));
                    sv = MFMA32(kf, qf[ks], sv);
                }
                __builtin_amdgcn_s_setprio(0);
            }

            // online softmax, defer-max THR=5; lane owns row i=li (dup g).
            float tmax = sv[0];
            #pragma unroll
            for (int e = 1; e < 16; ++e) tmax = fmaxf(tmax, sv[e]);
            tmax = fmaxf(tmax, __shfl_xor(tmax, 32));
            float sc_new = 1.0f;
            if (!__all((int)(tmax - m_run <= 5.f))) {
                const float mnew = fmaxf(m_run, tmax);
                sc_new = __expf(m_run - mnew);   // first slot: exp(-inf)=0
                l_run *= sc_new;
                m_run = mnew;
            }
            float p[16];
            float rs = 0.f;
            #pragma unroll
            for (int e = 0; e < 16; ++e) { p[e] = __expf(sv[e] - m_run); rs += p[e]; }
            rs += __shfl_xor(rs, 32);
            l_run += rs;

            f16x8 pa0, pa1;
            #pragma unroll
            for (int e = 0; e < 8; ++e) {
                pa0[e] = (_Float16)p[e];
                pa1[e] = (_Float16)p[8 + e];
            }
            // publish P(s) + sc(s)
            char* pd = Pt[cur][rg] + l * 48;
            *(f16x8*)pd        = pa0;
            *(f16x8*)(pd + 16) = pa1;
            *(float*)(pd + 32) = sc_new;

            // apply own P(s-1)
            if (s > 0) {
                if (!__all((int)(sc_prev == 1.f))) rescale_acc<6>(oacc, sc_prev);
                __builtin_amdgcn_s_setprio(1);
                pv_step<6, 0>(oacc, Vt[cur ^ 1], li, g, paA, paB);
                __builtin_amdgcn_s_setprio(0);
            }
            paA = pa0; paB = pa1; sc_prev = sc_new;
        } else {
            // consumer: PV(s-1) from Pt[cur^1]
            if (s > 0) {
                const char* ps = Pt[cur ^ 1][rg] + l * 48;
                f16x8 pa0 = *(const f16x8*)ps;
                f16x8 pa1 = *(const f16x8*)(ps + 16);
                const float sc = *(const float*)(ps + 32);
                if (!__all((int)(sc == 1.f))) rescale_acc<10>(oacc, sc);
                __builtin_amdgcn_s_setprio(1);
                pv_step<10, 192>(oacc, Vt[cur ^ 1], li, g, pa0, pa1);
                __builtin_amdgcn_s_setprio(0);
            }
        }
        __syncthreads();
    }

    // drain slot: tile 63 (Vt[1], Pt[1])
    if (ch == 0) {
        if (!__all((int)(sc_prev == 1.f))) rescale_acc<6>(oacc, sc_prev);
        pv_step<6, 0>(oacc, Vt[1], li, g, paA, paB);
    } else {
        const char* ps = Pt[1][rg] + l * 48;
        f16x8 pa0 = *(const f16x8*)ps;
        f16x8 pa1 = *(const f16x8*)(ps + 16);
        const float sc = *(const float*)(ps + 32);
        if (!__all((int)(sc == 1.f))) rescale_acc<10>(oacc, sc);
        pv_step<10, 192>(oacc, Vt[1], li, g, pa0, pa1);
    }

    // epilogue: O^T partial (c-major) + stats
    const size_t ob = (size_t)(jh * 4 + b) * CIN * NPIX;
    if (ch == 0) {
        #pragma unroll
        for (int ct = 0; ct < 6; ++ct)
            #pragma unroll
            for (int r = 0; r < 16; ++r) {
                const int c = ct * 32 + (r & 3) + 8 * (r >> 2) + 4 * g;
                opart[ob + (size_t)c * NPIX + i_row] = (_Float16)oacc[ct][r];
            }
        if (g == 0) {
            const size_t idx = ((size_t)(jh * 4 + b) * NPIX + i_row) * 2;
            stats[idx]     = m_run;
            stats[idx + 1] = l_run;
        }
    } else {
        #pragma unroll
        for (int ct = 0; ct < 10; ++ct)
            #pragma unroll
            for (int r = 0; r < 16; ++r) {
                const int c = 192 + ct * 32 + (r & 3) + 8 * (r >> 2) + 4 * g;
                opart[ob + (size_t)c * NPIX + i_row] = (_Float16)oacc[ct][r];
            }
    }
}

// ---------------------------------------------------------------------------
// Combine j-half partials (both c-major): no transpose needed.
// ---------------------------------------------------------------------------
__global__ __launch_bounds__(256) void combine_kernel(
    const _Float16* __restrict__ opart, const float* __restrict__ stats,
    float* __restrict__ out)
{
    const int b  = blockIdx.y;
    const int i0 = blockIdx.x * 64;
    const int t  = threadIdx.x;

    __shared__ float a0s[64], a1s[64];
    if (t < 64) {
        const int i = i0 + t;
        const size_t r0 = ((size_t)b * NPIX + i) * 2;
        const size_t r1 = ((size_t)(4 + b) * NPIX + i) * 2;
        const float m0 = stats[r0], l0 = stats[r0 + 1];
        const float m1 = stats[r1], l1 = stats[r1 + 1];
        const float M  = fmaxf(m0, m1);
        const float w0 = __expf(m0 - M), w1 = __expf(m1 - M);
        const float inv = 1.0f / (l0 * w0 + l1 * w1);
        a0s[t] = w0 * inv;
        a1s[t] = w1 * inv;
    }
    __syncthreads();

    const int ci = t >> 3;
    const int ii = (t & 7) * 8;
    #pragma unroll 4
    for (int pp = 0; pp < 16; ++pp) {
        const int c = pp * 32 + ci;
        const _Float16* p0 = opart + ((size_t)b * CIN + c) * NPIX + i0 + ii;
        const _Float16* p1 = opart + ((size_t)(4 + b) * CIN + c) * NPIX + i0 + ii;
        const f16x8 x0 = *(const f16x8*)p0;
        const f16x8 x1 = *(const f16x8*)p1;
        float* dst = out + ((size_t)b * CIN + c) * NPIX + i0 + ii;
        float4 o0, o1;
        o0.x = a0s[ii + 0] * (float)x0[0] + a1s[ii + 0] * (float)x1[0];
        o0.y = a0s[ii + 1] * (float)x0[1] + a1s[ii + 1] * (float)x1[1];
        o0.z = a0s[ii + 2] * (float)x0[2] + a1s[ii + 2] * (float)x1[2];
        o0.w = a0s[ii + 3] * (float)x0[3] + a1s[ii + 3] * (float)x1[3];
        o1.x = a0s[ii + 4] * (float)x0[4] + a1s[ii + 4] * (float)x1[4];
        o1.y = a0s[ii + 5] * (float)x0[5] + a1s[ii + 5] * (float)x1[5];
        o1.z = a0s[ii + 6] * (float)x0[6] + a1s[ii + 6] * (float)x1[6];
        o1.w = a0s[ii + 7] * (float)x0[7] + a1s[ii + 7] * (float)x1[7];
        *(float4*)dst       = o0;
        *(float4*)(dst + 4) = o1;
    }
}

// ---------------------------------------------------------------------------
extern "C" void kernel_launch(void* const* d_in, const int* in_sizes, int n_in,
                              void* d_out, int out_size, void* d_ws,
                              size_t ws_size, hipStream_t stream)
{
    const float* x   = (const float*)d_in[0];
    const float* f_w = (const float*)d_in[1];
    const float* f_b = (const float*)d_in[2];
    const float* g_w = (const float*)d_in[3];
    const float* g_b = (const float*)d_in[4];
    const float* h_w = (const float*)d_in[5];
    const float* h_b = (const float*)d_in[6];
    float* out = (float*)d_out;

    _Float16* qw = (_Float16*)d_ws;
    _Float16* kw = qw + (size_t)4 * NPIX * 256;
    _Float16* vw = kw + (size_t)4 * NPIX * 256;
    _Float16* op = vw + (size_t)4 * CIN * NPIX;
    float* stats = (float*)(op + (size_t)2 * 4 * CIN * NPIX);

    proj_kernel<<<dim3(64, 16, 4), 256, 0, stream>>>(
        x, f_w, f_b, g_w, g_b, h_w, h_b, qw, kw, vw);
    attn_kernel<<<dim3(256), 512, 0, stream>>>(qw, kw, vw, op, stats);
    combine_kernel<<<dim3(64, 4), 256, 0, stream>>>(op, stats, out);
}

// Round 7
// 320.414 us; speedup vs baseline: 1.4270x; 1.4270x over previous
//
#include <hip/hip_runtime.h>

// SelfAttention (SAGAN-style), MI355X gfx950.
// proj (f16 MFMA GEMM) -> flash attn (32x32x16 swapped-operand, QK on ch0
// waves only, P shared via LDS, counted-vmcnt raw barriers) -> combine.
//
// ws layout (~64.5 MB):
//   qw  f16 [4][4096][256]    8 MB  (Q rows)
//   kw  f16 [4][4096][256]    8 MB  (K rows)
//   vw  f16 [4][512][4096]   16 MB  (V, c-major)
//   op  f16 [2][4][512][4096] 32 MB (unnormalized O^T partials, c-major)
//   st  f32 [2][4][4096][2]  0.5 MB (m, l per row per j-half)

#define NPIX 4096
#define CIN  512

typedef _Float16 f16x4 __attribute__((ext_vector_type(4)));
typedef _Float16 f16x8 __attribute__((ext_vector_type(8)));
typedef float    f32x4 __attribute__((ext_vector_type(4)));
typedef float    f32x16 __attribute__((ext_vector_type(16)));

#define MFMA16(a, b, c) __builtin_amdgcn_mfma_f32_16x16x16f16(a, b, c, 0, 0, 0)
#define MFMA32(a, b, c) __builtin_amdgcn_mfma_f32_32x32x16_f16(a, b, c, 0, 0, 0)

__device__ __forceinline__ void gld_lds16(const void* g, void* l) {
    __builtin_amdgcn_global_load_lds(
        (const __attribute__((address_space(1))) unsigned int*)g,
        (__attribute__((address_space(3))) unsigned int*)l, 16, 0, 0);
}

// ---------------------------------------------------------------------------
// Projection: out[o][n], o<256->Q, <512->K, else->V.
// ---------------------------------------------------------------------------
__global__ __launch_bounds__(256) void proj_kernel(
    const float* __restrict__ x,
    const float* __restrict__ f_w, const float* __restrict__ f_b,
    const float* __restrict__ g_w, const float* __restrict__ g_b,
    const float* __restrict__ h_w, const float* __restrict__ h_b,
    _Float16* __restrict__ qw, _Float16* __restrict__ kw,
    _Float16* __restrict__ vw)
{
    const int b  = blockIdx.z;
    const int n0 = blockIdx.x * 64;
    const int o0 = blockIdx.y * 64;

    const float* wsrc; const float* bsrc;
    if (o0 < 256)      { wsrc = f_w + (size_t)o0 * CIN;         bsrc = f_b + o0; }
    else if (o0 < 512) { wsrc = g_w + (size_t)(o0 - 256) * CIN; bsrc = g_b + (o0 - 256); }
    else               { wsrc = h_w + (size_t)(o0 - 512) * CIN; bsrc = h_b + (o0 - 512); }

    __shared__ _Float16 Wt[64][40];
    __shared__ _Float16 Xt[64][40];

    const int t = threadIdx.x;
    const int lane = t & 63, wv = t >> 6;
    const int wm = wv >> 1, wn = wv & 1;
    const int gi = lane >> 4, li = lane & 15;

    f32x4 acc[2][2];
    #pragma unroll
    for (int i = 0; i < 2; ++i)
        #pragma unroll
        for (int j = 0; j < 2; ++j) acc[i][j] = f32x4{0.f, 0.f, 0.f, 0.f};

    for (int kk = 0; kk < CIN; kk += 32) {
        {   // W tile 64x32: one b128 store per thread
            const int r = t >> 2, c8 = (t & 3) * 8;
            const float* p = wsrc + (size_t)r * CIN + kk + c8;
            const float4 v0 = *(const float4*)p;
            const float4 v1 = *(const float4*)(p + 4);
            f16x8 w8;
            w8[0] = (_Float16)v0.x; w8[1] = (_Float16)v0.y;
            w8[2] = (_Float16)v0.z; w8[3] = (_Float16)v0.w;
            w8[4] = (_Float16)v1.x; w8[5] = (_Float16)v1.y;
            w8[6] = (_Float16)v1.z; w8[7] = (_Float16)v1.w;
            *(f16x8*)&Wt[r][c8] = w8;
        }
        {   // X tile 32c x 64n: 8 coalesced dword loads, 1 b128 store
            const int cb = (t >> 6) * 8;
            const int nl = t & 63;
            f16x8 xv;
            #pragma unroll
            for (int e = 0; e < 8; ++e)
                xv[e] = (_Float16)x[((size_t)b * CIN + kk + cb + e) * NPIX +
                                    n0 + nl];
            *(f16x8*)&Xt[nl][cb] = xv;
        }
        __syncthreads();
        #pragma unroll
        for (int kh = 0; kh < 2; ++kh) {
            const int ko = kh * 16 + gi * 4;
            f16x4 a0 = *(const f16x4*)&Wt[wm * 32 +      li][ko];
            f16x4 a1 = *(const f16x4*)&Wt[wm * 32 + 16 + li][ko];
            f16x4 b0 = *(const f16x4*)&Xt[wn * 32 +      li][ko];
            f16x4 b1 = *(const f16x4*)&Xt[wn * 32 + 16 + li][ko];
            acc[0][0] = MFMA16(a0, b0, acc[0][0]);
            acc[0][1] = MFMA16(a0, b1, acc[0][1]);
            acc[1][0] = MFMA16(a1, b0, acc[1][0]);
            acc[1][1] = MFMA16(a1, b1, acc[1][1]);
        }
        __syncthreads();
    }

    #pragma unroll
    for (int mf = 0; mf < 2; ++mf)
        #pragma unroll
        for (int nf = 0; nf < 2; ++nf) {
            const int obase = o0 + wm * 32 + mf * 16 + gi * 4;
            const int n     = n0 + wn * 32 + nf * 16 + li;
            const int brel  = wm * 32 + mf * 16 + gi * 4;
            float v[4];
            #pragma unroll
            for (int r = 0; r < 4; ++r) v[r] = acc[mf][nf][r] + bsrc[brel + r];
            if (o0 < 512) {
                _Float16* dst = (o0 < 256) ? qw : kw;
                const int kb  = (o0 < 256) ? obase : (obase - 256);
                f16x4 pk;
                pk[0] = (_Float16)v[0]; pk[1] = (_Float16)v[1];
                pk[2] = (_Float16)v[2]; pk[3] = (_Float16)v[3];
                *(f16x4*)&dst[((size_t)b * NPIX + n) * 256 + kb] = pk;
            } else {
                #pragma unroll
                for (int r = 0; r < 4; ++r)
                    vw[((size_t)b * CIN + (obase - 512 + r)) * NPIX + n] =
                        (_Float16)v[r];
            }
        }
}

// ---------------------------------------------------------------------------
// Flash attention, one j-half (2048 keys). 8 waves = 4 row-groups x 2 c-halves
// (ch = wv&1: producer pairs share SIMDs for QK-phase latency hiding).
// Only ch=0 computes QK+softmax; P fragments shared via single-buffer LDS.
// Counted-vmcnt discipline (m201 template): raw s_barrier, vmcnt(6) gate
// after issuing this iter's 6 VMEM ops, lgkmcnt(0) before each barrier.
// Loads for tile s+1 stay in flight across both barriers of iter s.
// ---------------------------------------------------------------------------
__global__ __launch_bounds__(512, 2) void attn_kernel(
    const _Float16* __restrict__ qw, const _Float16* __restrict__ kw,
    const _Float16* __restrict__ vw,
    _Float16* __restrict__ opart, float* __restrict__ stats)
{
    const int bid = blockIdx.x;
    const int xcd = bid & 7;
    const int jh = xcd & 1, b = xcd >> 1;
    const int rb = bid >> 3;
    const int t = threadIdx.x, l = t & 63, wv = t >> 6;
    const int li = l & 31, g = l >> 5;
    const int ch = wv & 1, rg = wv >> 1;
    const int i_row = rb * 128 + rg * 32 + li;

    __shared__ char Kt[2][16384];        // 32 rows x 512B, XOR-swizzled
    __shared__ char Vt[2][512 * 72];     // 512 rows x 64B data + 8B pad
    __shared__ char Pt[4][64 * 48];      // per lane: pa0(16) pa1(16) sc(4)

    // Q fragments (producers only)
    f16x8 qf[16];
    if (ch == 0) {
        const _Float16* qb = qw + ((size_t)b * NPIX + i_row) * 256 + 8 * g;
        #pragma unroll
        for (int ks = 0; ks < 16; ++ks) qf[ks] = *(const f16x8*)(qb + ks * 16);
    }

    f32x16 oacc[8];
    #pragma unroll
    for (int i = 0; i < 8; ++i)
        #pragma unroll
        for (int e = 0; e < 16; ++e) oacc[i][e] = 0.f;
    float m_run = -__builtin_inff();
    float l_run = 0.f;

    f16x8 vreg[4];

    auto stageK = [&](int buf, int j0) {
        #pragma unroll
        for (int q = 0; q < 2; ++q) {
            const int slot = q * 512 + t;
            const int row  = slot >> 5;
            const int colb = (slot & 31) * 16;
            const char* src =
                (const char*)(kw + ((size_t)b * NPIX + j0 + row) * 256) +
                (colb ^ ((row & 31) << 4));
            gld_lds16(src, Kt[buf] + slot * 16);
        }
    };
    auto loadV = [&](int j0) {
        #pragma unroll
        for (int q = 0; q < 4; ++q) {
            const int c  = q * 128 + (t >> 2);
            const int jj = (t & 3) * 8;
            vreg[q] = *(const f16x8*)(vw + ((size_t)b * CIN + c) * NPIX + j0 + jj);
        }
    };
    auto writeV = [&](int buf) {
        #pragma unroll
        for (int q = 0; q < 4; ++q) {
            const int c = q * 128 + (t >> 2);
            char* d = Vt[buf] + c * 72 + (t & 3) * 16;
            *(f16x4*)d       = *(f16x4*)&vreg[q];
            *(f16x4*)(d + 8) = *((f16x4*)&vreg[q] + 1);
        }
    };

    const int jbase = jh * 2048;
    loadV(jbase);        // tile 0 V -> vreg
    stageK(0, jbase);    // tile 0 K -> Kt[0] (DMA)
    writeV(0);           // vreg -> Vt[0] (compiler waits vmcnt for vreg)
    __syncthreads();     // prologue: full drain once

    for (int s = 0; s < 64; ++s) {
        const int cur = s & 1;

        // issue next tile's 6 VMEM ops, then gate on the PREVIOUS iter's
        if (s < 63) {
            loadV(jbase + (s + 1) * 32);            // 4 vm (oldest of this iter)
            stageK(cur ^ 1, jbase + (s + 1) * 32);  // 2 vm
            asm volatile("s_waitcnt vmcnt(6)" ::: "memory");
        } else {
            asm volatile("s_waitcnt vmcnt(0)" ::: "memory");
        }
        __builtin_amdgcn_sched_barrier(0);
        __builtin_amdgcn_s_barrier();   // TOP: Kt[cur] staged, Vt[cur] visible

        if (ch == 0) {
            // QK^T: S^T[j][i]; A = K row j=li, B = Q col i=li.
            f32x16 sv;
            #pragma unroll
            for (int e = 0; e < 16; ++e) sv[e] = 0.f;
            {
                const char* kr = Kt[cur] + li * 512;
                const int sw = li << 4;
                __builtin_amdgcn_s_setprio(1);
                #pragma unroll
                for (int ks = 0; ks < 16; ++ks) {
                    f16x8 kf = *(const f16x8*)(kr + ((ks * 32 + 16 * g) ^ sw));
                    sv = MFMA32(kf, qf[ks], sv);
                }
                __builtin_amdgcn_s_setprio(0);
            }

            // online softmax, defer-max THR=5; lane owns row i=li (dup g).
            float tmax = sv[0];
            #pragma unroll
            for (int e = 1; e < 16; ++e) tmax = fmaxf(tmax, sv[e]);
            tmax = fmaxf(tmax, __shfl_xor(tmax, 32));
            float sc_my = 1.0f;
            if (!__all((int)(tmax - m_run <= 5.f))) {
                const float mnew = fmaxf(m_run, tmax);
                sc_my = __expf(m_run - mnew);   // first iter: exp(-inf)=0
                #pragma unroll
                for (int ct = 0; ct < 8; ++ct)
                    #pragma unroll
                    for (int e = 0; e < 16; ++e) oacc[ct][e] *= sc_my;
                l_run *= sc_my;
                m_run = mnew;
            }
            float p[16];
            float rs = 0.f;
            #pragma unroll
            for (int e = 0; e < 16; ++e) { p[e] = __expf(sv[e] - m_run); rs += p[e]; }
            rs += __shfl_xor(rs, 32);
            l_run += rs;

            f16x8 pa0, pa1;
            #pragma unroll
            for (int e = 0; e < 8; ++e) {
                pa0[e] = (_Float16)p[e];
                pa1[e] = (_Float16)p[8 + e];
            }
            // publish P + sc for the ch=1 partner wave
            char* pd = Pt[rg] + l * 48;
            *(f16x8*)pd        = pa0;
            *(f16x8*)(pd + 16) = pa1;
            *(float*)(pd + 32) = sc_my;

            asm volatile("s_waitcnt lgkmcnt(0)" ::: "memory");
            __builtin_amdgcn_s_barrier();   // MID: P visible

            // PV: own c-half (c 0..255)
            __builtin_amdgcn_s_setprio(1);
            #pragma unroll
            for (int ct = 0; ct < 8; ++ct) {
                const int c = ct * 32 + li;
                const char* vr = Vt[cur] + c * 72;
                f16x8 va, vc;
                *(f16x4*)&va       = *(const f16x4*)(vr + 8 * g);
                *((f16x4*)&va + 1) = *(const f16x4*)(vr + 16 + 8 * g);
                oacc[ct] = MFMA32(va, pa0, oacc[ct]);
                *(f16x4*)&vc       = *(const f16x4*)(vr + 32 + 8 * g);
                *((f16x4*)&vc + 1) = *(const f16x4*)(vr + 48 + 8 * g);
                oacc[ct] = MFMA32(vc, pa1, oacc[ct]);
            }
            __builtin_amdgcn_s_setprio(0);
        } else {
            asm volatile("s_waitcnt lgkmcnt(0)" ::: "memory");
            __builtin_amdgcn_s_barrier();   // MID (consumers arrive here)

            const char* ps = Pt[rg] + l * 48;
            f16x8 pa0 = *(const f16x8*)ps;
            f16x8 pa1 = *(const f16x8*)(ps + 16);
            const float sc = *(const float*)(ps + 32);
            if (!__all((int)(sc == 1.0f))) {
                #pragma unroll
                for (int ct = 0; ct < 8; ++ct)
                    #pragma unroll
                    for (int e = 0; e < 16; ++e) oacc[ct][e] *= sc;
            }
            // PV: c-half (c 256..511)
            __builtin_amdgcn_s_setprio(1);
            #pragma unroll
            for (int ct = 0; ct < 8; ++ct) {
                const int c = 256 + ct * 32 + li;
                const char* vr = Vt[cur] + c * 72;
                f16x8 va, vc;
                *(f16x4*)&va       = *(const f16x4*)(vr + 8 * g);
                *((f16x4*)&va + 1) = *(const f16x4*)(vr + 16 + 8 * g);
                oacc[ct] = MFMA32(va, pa0, oacc[ct]);
                *(f16x4*)&vc       = *(const f16x4*)(vr + 32 + 8 * g);
                *((f16x4*)&vc + 1) = *(const f16x4*)(vr + 48 + 8 * g);
                oacc[ct] = MFMA32(vc, pa1, oacc[ct]);
            }
            __builtin_amdgcn_s_setprio(0);
        }

        // stage next V tile (Vt[cur^1] readers all passed TOP of this iter)
        if (s < 63) writeV(cur ^ 1);
        asm volatile("s_waitcnt lgkmcnt(0)" ::: "memory");
        __builtin_amdgcn_sched_barrier(0);
        // loop closes at next iter's TOP barrier (no BOT barrier needed:
        // writeV(cur^1) WAR vs iter s-1 readers separated by TOP(s);
        // Pt WAR separated by TOP(s+1)).
    }

    // epilogue: O^T partial (c-major) + stats
    const size_t ob = (size_t)(jh * 4 + b) * CIN * NPIX;
    #pragma unroll
    for (int ct = 0; ct < 8; ++ct)
        #pragma unroll
        for (int r = 0; r < 16; ++r) {
            const int c = ch * 256 + ct * 32 + (r & 3) + 8 * (r >> 2) + 4 * g;
            opart[ob + (size_t)c * NPIX + i_row] = (_Float16)oacc[ct][r];
        }
    if (ch == 0 && g == 0) {
        const size_t idx = ((size_t)(jh * 4 + b) * NPIX + i_row) * 2;
        stats[idx]     = m_run;
        stats[idx + 1] = l_run;
    }
}

// ---------------------------------------------------------------------------
// Combine j-half partials (both c-major): no transpose needed.
// ---------------------------------------------------------------------------
__global__ __launch_bounds__(256) void combine_kernel(
    const _Float16* __restrict__ opart, const float* __restrict__ stats,
    float* __restrict__ out)
{
    const int b  = blockIdx.y;
    const int i0 = blockIdx.x * 64;
    const int t  = threadIdx.x;

    __shared__ float a0s[64], a1s[64];
    if (t < 64) {
        const int i = i0 + t;
        const size_t r0 = ((size_t)b * NPIX + i) * 2;
        const size_t r1 = ((size_t)(4 + b) * NPIX + i) * 2;
        const float m0 = stats[r0], l0 = stats[r0 + 1];
        const float m1 = stats[r1], l1 = stats[r1 + 1];
        const float M  = fmaxf(m0, m1);
        const float w0 = __expf(m0 - M), w1 = __expf(m1 - M);
        const float inv = 1.0f / (l0 * w0 + l1 * w1);
        a0s[t] = w0 * inv;
        a1s[t] = w1 * inv;
    }
    __syncthreads();

    const int ci = t >> 3;
    const int ii = (t & 7) * 8;
    #pragma unroll 4
    for (int pp = 0; pp < 16; ++pp) {
        const int c = pp * 32 + ci;
        const _Float16* p0 = opart + ((size_t)b * CIN + c) * NPIX + i0 + ii;
        const _Float16* p1 = opart + ((size_t)(4 + b) * CIN + c) * NPIX + i0 + ii;
        const f16x8 x0 = *(const f16x8*)p0;
        const f16x8 x1 = *(const f16x8*)p1;
        float* dst = out + ((size_t)b * CIN + c) * NPIX + i0 + ii;
        float4 o0, o1;
        o0.x = a0s[ii + 0] * (float)x0[0] + a1s[ii + 0] * (float)x1[0];
        o0.y = a0s[ii + 1] * (float)x0[1] + a1s[ii + 1] * (float)x1[1];
        o0.z = a0s[ii + 2] * (float)x0[2] + a1s[ii + 2] * (float)x1[2];
        o0.w = a0s[ii + 3] * (float)x0[3] + a1s[ii + 3] * (float)x1[3];
        o1.x = a0s[ii + 4] * (float)x0[4] + a1s[ii + 4] * (float)x1[4];
        o1.y = a0s[ii + 5] * (float)x0[5] + a1s[ii + 5] * (float)x1[5];
        o1.z = a0s[ii + 6] * (float)x0[6] + a1s[ii + 6] * (float)x1[6];
        o1.w = a0s[ii + 7] * (float)x0[7] + a1s[ii + 7] * (float)x1[7];
        *(float4*)dst       = o0;
        *(float4*)(dst + 4) = o1;
    }
}

// ---------------------------------------------------------------------------
extern "C" void kernel_launch(void* const* d_in, const int* in_sizes, int n_in,
                              void* d_out, int out_size, void* d_ws,
                              size_t ws_size, hipStream_t stream)
{
    const float* x   = (const float*)d_in[0];
    const float* f_w = (const float*)d_in[1];
    const float* f_b = (const float*)d_in[2];
    const float* g_w = (const float*)d_in[3];
    const float* g_b = (const float*)d_in[4];
    const float* h_w = (const float*)d_in[5];
    const float* h_b = (const float*)d_in[6];
    float* out = (float*)d_out;

    _Float16* qw = (_Float16*)d_ws;
    _Float16* kw = qw + (size_t)4 * NPIX * 256;
    _Float16* vw = kw + (size_t)4 * NPIX * 256;
    _Float16* op = vw + (size_t)4 * CIN * NPIX;
    float* stats = (float*)(op + (size_t)2 * 4 * CIN * NPIX);

    proj_kernel<<<dim3(64, 16, 4), 256, 0, stream>>>(
        x, f_w, f_b, g_w, g_b, h_w, h_b, qw, kw, vw);
    attn_kernel<<<dim3(256), 512, 0, stream>>>(qw, kw, vw, op, stats);
    combine_kernel<<<dim3(64, 4), 256, 0, stream>>>(op, stats, out);
}

// Round 8
// 236.849 us; speedup vs baseline: 1.9305x; 1.3528x over previous
//
#include <hip/hip_runtime.h>

// SelfAttention (SAGAN-style), MI355X gfx950.
// proj (f16 MFMA GEMM) -> flash attn (32x32x16 swapped-operand; role-split
// waves: producers QK+softmax / consumers V-staging+PV; SIMD-paired) -> combine.
//
// ws layout (~64.5 MB):
//   qw  f16 [4][4096][256]    8 MB  (Q rows)
//   kw  f16 [4][4096][256]    8 MB  (K rows)
//   vw  f16 [4][512][4096]   16 MB  (V, c-major)
//   op  f16 [2][4][512][4096] 32 MB (unnormalized O^T partials, c-major)
//   st  f32 [2][4][4096][2]  0.5 MB (m, l per row per j-half)

#define NPIX 4096
#define CIN  512

typedef _Float16 f16x4 __attribute__((ext_vector_type(4)));
typedef _Float16 f16x8 __attribute__((ext_vector_type(8)));
typedef float    f32x4 __attribute__((ext_vector_type(4)));
typedef float    f32x16 __attribute__((ext_vector_type(16)));

#define MFMA16(a, b, c) __builtin_amdgcn_mfma_f32_16x16x16f16(a, b, c, 0, 0, 0)
#define MFMA32(a, b, c) __builtin_amdgcn_mfma_f32_32x32x16_f16(a, b, c, 0, 0, 0)

__device__ __forceinline__ void gld_lds16(const void* g, void* l) {
    __builtin_amdgcn_global_load_lds(
        (const __attribute__((address_space(1))) unsigned int*)g,
        (__attribute__((address_space(3))) unsigned int*)l, 16, 0, 0);
}

// ---------------------------------------------------------------------------
// Projection: out[o][n], o<256->Q, <512->K, else->V.
// ---------------------------------------------------------------------------
__global__ __launch_bounds__(256) void proj_kernel(
    const float* __restrict__ x,
    const float* __restrict__ f_w, const float* __restrict__ f_b,
    const float* __restrict__ g_w, const float* __restrict__ g_b,
    const float* __restrict__ h_w, const float* __restrict__ h_b,
    _Float16* __restrict__ qw, _Float16* __restrict__ kw,
    _Float16* __restrict__ vw)
{
    const int b  = blockIdx.z;
    const int n0 = blockIdx.x * 64;
    const int o0 = blockIdx.y * 64;

    const float* wsrc; const float* bsrc;
    if (o0 < 256)      { wsrc = f_w + (size_t)o0 * CIN;         bsrc = f_b + o0; }
    else if (o0 < 512) { wsrc = g_w + (size_t)(o0 - 256) * CIN; bsrc = g_b + (o0 - 256); }
    else               { wsrc = h_w + (size_t)(o0 - 512) * CIN; bsrc = h_b + (o0 - 512); }

    __shared__ _Float16 Wt[64][40];
    __shared__ _Float16 Xt[64][40];

    const int t = threadIdx.x;
    const int lane = t & 63, wv = t >> 6;
    const int wm = wv >> 1, wn = wv & 1;
    const int gi = lane >> 4, li = lane & 15;

    f32x4 acc[2][2];
    #pragma unroll
    for (int i = 0; i < 2; ++i)
        #pragma unroll
        for (int j = 0; j < 2; ++j) acc[i][j] = f32x4{0.f, 0.f, 0.f, 0.f};

    for (int kk = 0; kk < CIN; kk += 32) {
        {   // W tile 64x32: one b128 store per thread
            const int r = t >> 2, c8 = (t & 3) * 8;
            const float* p = wsrc + (size_t)r * CIN + kk + c8;
            const float4 v0 = *(const float4*)p;
            const float4 v1 = *(const float4*)(p + 4);
            f16x8 w8;
            w8[0] = (_Float16)v0.x; w8[1] = (_Float16)v0.y;
            w8[2] = (_Float16)v0.z; w8[3] = (_Float16)v0.w;
            w8[4] = (_Float16)v1.x; w8[5] = (_Float16)v1.y;
            w8[6] = (_Float16)v1.z; w8[7] = (_Float16)v1.w;
            *(f16x8*)&Wt[r][c8] = w8;
        }
        {   // X tile 32c x 64n: 8 coalesced dword loads, 1 b128 store
            const int cb = (t >> 6) * 8;
            const int nl = t & 63;
            f16x8 xv;
            #pragma unroll
            for (int e = 0; e < 8; ++e)
                xv[e] = (_Float16)x[((size_t)b * CIN + kk + cb + e) * NPIX +
                                    n0 + nl];
            *(f16x8*)&Xt[nl][cb] = xv;
        }
        __syncthreads();
        #pragma unroll
        for (int kh = 0; kh < 2; ++kh) {
            const int ko = kh * 16 + gi * 4;
            f16x4 a0 = *(const f16x4*)&Wt[wm * 32 +      li][ko];
            f16x4 a1 = *(const f16x4*)&Wt[wm * 32 + 16 + li][ko];
            f16x4 b0 = *(const f16x4*)&Xt[wn * 32 +      li][ko];
            f16x4 b1 = *(const f16x4*)&Xt[wn * 32 + 16 + li][ko];
            acc[0][0] = MFMA16(a0, b0, acc[0][0]);
            acc[0][1] = MFMA16(a0, b1, acc[0][1]);
            acc[1][0] = MFMA16(a1, b0, acc[1][0]);
            acc[1][1] = MFMA16(a1, b1, acc[1][1]);
        }
        __syncthreads();
    }

    #pragma unroll
    for (int mf = 0; mf < 2; ++mf)
        #pragma unroll
        for (int nf = 0; nf < 2; ++nf) {
            const int obase = o0 + wm * 32 + mf * 16 + gi * 4;
            const int n     = n0 + wn * 32 + nf * 16 + li;
            const int brel  = wm * 32 + mf * 16 + gi * 4;
            float v[4];
            #pragma unroll
            for (int r = 0; r < 4; ++r) v[r] = acc[mf][nf][r] + bsrc[brel + r];
            if (o0 < 512) {
                _Float16* dst = (o0 < 256) ? qw : kw;
                const int kb  = (o0 < 256) ? obase : (obase - 256);
                f16x4 pk;
                pk[0] = (_Float16)v[0]; pk[1] = (_Float16)v[1];
                pk[2] = (_Float16)v[2]; pk[3] = (_Float16)v[3];
                *(f16x4*)&dst[((size_t)b * NPIX + n) * 256 + kb] = pk;
            } else {
                #pragma unroll
                for (int r = 0; r < 4; ++r)
                    vw[((size_t)b * CIN + (obase - 512 + r)) * NPIX + n] =
                        (_Float16)v[r];
            }
        }
}

// ---------------------------------------------------------------------------
// Flash attention, one j-half (2048 keys). 8 waves, role-split:
//   producers wv0-3 (t<256): stage K (DMA), QK^T, softmax, publish P; PV c0-255
//   consumers wv4-7: stage V (reg, A-half pre-MID / B-half post-MID), PV c256-511
// ch = wv>>2 puts one producer + one consumer on each SIMD, so consumer MID
// wait overlaps producer QK on the same SIMD. One __syncthreads per iter.
// ---------------------------------------------------------------------------
__global__ __launch_bounds__(512, 2) void attn_kernel(
    const _Float16* __restrict__ qw, const _Float16* __restrict__ kw,
    const _Float16* __restrict__ vw,
    _Float16* __restrict__ opart, float* __restrict__ stats)
{
    const int bid = blockIdx.x;
    const int xcd = bid & 7;
    const int jh = xcd & 1, b = xcd >> 1;
    const int rb = bid >> 3;
    const int t = threadIdx.x, l = t & 63, wv = t >> 6;
    const int li = l & 31, g = l >> 5;
    const int ch = wv >> 2, rg = wv & 3;   // producers: wv0-3 (t<256)
    const int tc = t & 255;
    const int i_row = rb * 128 + rg * 32 + li;

    __shared__ char Kt[2][16384];        // 32 rows x 512B, XOR-swizzled
    __shared__ char Vt[2][512 * 72];     // 512 rows x 64B data + 8B pad
    __shared__ char Pt[2][4][64 * 48];   // per lane: pa0(16) pa1(16) sc(4)

    // Q fragments (producers only)
    f16x8 qf[16];
    if (ch == 0) {
        const _Float16* qb = qw + ((size_t)b * NPIX + i_row) * 256 + 8 * g;
        #pragma unroll
        for (int ks = 0; ks < 16; ++ks) qf[ks] = *(const f16x8*)(qb + ks * 16);
    }

    f32x16 oacc[8];
    #pragma unroll
    for (int i = 0; i < 8; ++i)
        #pragma unroll
        for (int e = 0; e < 16; ++e) oacc[i][e] = 0.f;
    float m_run = -__builtin_inff();
    float l_run = 0.f;

    f16x8 vreg[4];   // consumers: reused for A-half and B-half

    auto stageK = [&](int buf, int j0) {   // producers: 256 threads x 4 slots
        #pragma unroll
        for (int q = 0; q < 4; ++q) {
            const int slot = q * 256 + tc;
            const int row  = slot >> 5;
            const int colb = (slot & 31) * 16;
            const char* src =
                (const char*)(kw + ((size_t)b * NPIX + j0 + row) * 256) +
                (colb ^ ((row & 31) << 4));
            gld_lds16(src, Kt[buf] + slot * 16);
        }
    };
    auto loadVh = [&](int half, int j0) {  // consumers: 256 rows per half
        #pragma unroll
        for (int q = 0; q < 4; ++q) {
            const int c = half * 256 + q * 64 + (tc >> 2);
            vreg[q] = *(const f16x8*)(vw + ((size_t)b * CIN + c) * NPIX + j0 +
                                      (tc & 3) * 8);
        }
    };
    auto writeVh = [&](int buf, int half) {
        #pragma unroll
        for (int q = 0; q < 4; ++q) {
            const int c = half * 256 + q * 64 + (tc >> 2);
            char* d = Vt[buf] + c * 72 + (tc & 3) * 16;
            *(f16x4*)d       = *(f16x4*)&vreg[q];
            *(f16x4*)(d + 8) = *((f16x4*)&vreg[q] + 1);
        }
    };

    const int jbase = jh * 2048;
    if (ch == 0) {
        stageK(0, jbase);
    } else {
        loadVh(0, jbase); writeVh(0, 0);
        loadVh(1, jbase); writeVh(0, 1);
    }
    __syncthreads();

    for (int s = 0; s < 64; ++s) {
        const int cur = s & 1;
        f16x8 pa0, pa1;

        if (ch == 0) {
            if (s < 63) stageK(cur ^ 1, jbase + (s + 1) * 32);

            // QK^T: S^T[j][i]; A = K row j=li, B = Q col i=li.
            f32x16 sv;
            #pragma unroll
            for (int e = 0; e < 16; ++e) sv[e] = 0.f;
            {
                const char* kr = Kt[cur] + li * 512;
                const int sw = li << 4;
                __builtin_amdgcn_s_setprio(1);
                #pragma unroll
                for (int ks = 0; ks < 16; ++ks) {
                    f16x8 kf = *(const f16x8*)(kr + ((ks * 32 + 16 * g) ^ sw));
                    sv = MFMA32(kf, qf[ks], sv);
                }
                __builtin_amdgcn_s_setprio(0);
            }

            // online softmax, defer-max THR=5; lane owns row i=li (dup g).
            float tmax = sv[0];
            #pragma unroll
            for (int e = 1; e < 16; ++e) tmax = fmaxf(tmax, sv[e]);
            tmax = fmaxf(tmax, __shfl_xor(tmax, 32));
            float sc_my = 1.0f;
            if (!__all((int)(tmax - m_run <= 5.f))) {
                const float mnew = fmaxf(m_run, tmax);
                sc_my = __expf(m_run - mnew);   // first iter: exp(-inf)=0
                #pragma unroll
                for (int ct = 0; ct < 8; ++ct)
                    #pragma unroll
                    for (int e = 0; e < 16; ++e) oacc[ct][e] *= sc_my;
                l_run *= sc_my;
                m_run = mnew;
            }
            float p[16];
            float rs = 0.f;
            #pragma unroll
            for (int e = 0; e < 16; ++e) { p[e] = __expf(sv[e] - m_run); rs += p[e]; }
            rs += __shfl_xor(rs, 32);
            l_run += rs;

            #pragma unroll
            for (int e = 0; e < 8; ++e) {
                pa0[e] = (_Float16)p[e];
                pa1[e] = (_Float16)p[8 + e];
            }
            // publish P + sc for the consumer waves
            char* pd = Pt[cur][rg] + l * 48;
            *(f16x8*)pd        = pa0;
            *(f16x8*)(pd + 16) = pa1;
            *(float*)(pd + 32) = sc_my;
        } else {
            // consumers: issue next tile's A-half loads (overlaps producer QK)
            if (s < 63) loadVh(0, jbase + (s + 1) * 32);
        }

        __syncthreads();   // MID: P visible; Kt[cur^1] DMA drained; PV(s-1) done

        if (ch == 0) {
            // PV: c 0..255 with own P
            __builtin_amdgcn_s_setprio(1);
            #pragma unroll
            for (int ct = 0; ct < 8; ++ct) {
                const int c = ct * 32 + li;
                const char* vr = Vt[cur] + c * 72;
                f16x8 va, vc;
                *(f16x4*)&va       = *(const f16x4*)(vr + 8 * g);
                *((f16x4*)&va + 1) = *(const f16x4*)(vr + 16 + 8 * g);
                oacc[ct] = MFMA32(va, pa0, oacc[ct]);
                *(f16x4*)&vc       = *(const f16x4*)(vr + 32 + 8 * g);
                *((f16x4*)&vc + 1) = *(const f16x4*)(vr + 48 + 8 * g);
                oacc[ct] = MFMA32(vc, pa1, oacc[ct]);
            }
            __builtin_amdgcn_s_setprio(0);
        } else {
            // write A-half of next tile (loads issued pre-MID, long complete)
            if (s < 63) {
                writeVh(cur ^ 1, 0);
                loadVh(1, jbase + (s + 1) * 32);   // B-half issue (PV hides it)
            }
            const char* ps = Pt[cur][rg] + l * 48;
            pa0 = *(const f16x8*)ps;
            pa1 = *(const f16x8*)(ps + 16);
            const float sc = *(const float*)(ps + 32);
            if (!__all((int)(sc == 1.0f))) {
                #pragma unroll
                for (int ct = 0; ct < 8; ++ct)
                    #pragma unroll
                    for (int e = 0; e < 16; ++e) oacc[ct][e] *= sc;
            }
            // PV: c 256..511
            __builtin_amdgcn_s_setprio(1);
            #pragma unroll
            for (int ct = 0; ct < 8; ++ct) {
                const int c = 256 + ct * 32 + li;
                const char* vr = Vt[cur] + c * 72;
                f16x8 va, vc;
                *(f16x4*)&va       = *(const f16x4*)(vr + 8 * g);
                *((f16x4*)&va + 1) = *(const f16x4*)(vr + 16 + 8 * g);
                oacc[ct] = MFMA32(va, pa0, oacc[ct]);
                *(f16x4*)&vc       = *(const f16x4*)(vr + 32 + 8 * g);
                *((f16x4*)&vc + 1) = *(const f16x4*)(vr + 48 + 8 * g);
                oacc[ct] = MFMA32(vc, pa1, oacc[ct]);
            }
            __builtin_amdgcn_s_setprio(0);
            if (s < 63) writeVh(cur ^ 1, 1);
        }
    }

    // epilogue: O^T partial (c-major) + stats
    const size_t ob = (size_t)(jh * 4 + b) * CIN * NPIX;
    #pragma unroll
    for (int ct = 0; ct < 8; ++ct)
        #pragma unroll
        for (int r = 0; r < 16; ++r) {
            const int c = ch * 256 + ct * 32 + (r & 3) + 8 * (r >> 2) + 4 * g;
            opart[ob + (size_t)c * NPIX + i_row] = (_Float16)oacc[ct][r];
        }
    if (ch == 0 && g == 0) {
        const size_t idx = ((size_t)(jh * 4 + b) * NPIX + i_row) * 2;
        stats[idx]     = m_run;
        stats[idx + 1] = l_run;
    }
}

// ---------------------------------------------------------------------------
// Combine j-half partials (both c-major): no transpose needed.
// ---------------------------------------------------------------------------
__global__ __launch_bounds__(256) void combine_kernel(
    const _Float16* __restrict__ opart, const float* __restrict__ stats,
    float* __restrict__ out)
{
    const int b  = blockIdx.y;
    const int i0 = blockIdx.x * 64;
    const int t  = threadIdx.x;

    __shared__ float a0s[64], a1s[64];
    if (t < 64) {
        const int i = i0 + t;
        const size_t r0 = ((size_t)b * NPIX + i) * 2;
        const size_t r1 = ((size_t)(4 + b) * NPIX + i) * 2;
        const float m0 = stats[r0], l0 = stats[r0 + 1];
        const float m1 = stats[r1], l1 = stats[r1 + 1];
        const float M  = fmaxf(m0, m1);
        const float w0 = __expf(m0 - M), w1 = __expf(m1 - M);
        const float inv = 1.0f / (l0 * w0 + l1 * w1);
        a0s[t] = w0 * inv;
        a1s[t] = w1 * inv;
    }
    __syncthreads();

    const int ci = t >> 3;
    const int ii = (t & 7) * 8;
    #pragma unroll 4
    for (int pp = 0; pp < 16; ++pp) {
        const int c = pp * 32 + ci;
        const _Float16* p0 = opart + ((size_t)b * CIN + c) * NPIX + i0 + ii;
        const _Float16* p1 = opart + ((size_t)(4 + b) * CIN + c) * NPIX + i0 + ii;
        const f16x8 x0 = *(const f16x8*)p0;
        const f16x8 x1 = *(const f16x8*)p1;
        float* dst = out + ((size_t)b * CIN + c) * NPIX + i0 + ii;
        float4 o0, o1;
        o0.x = a0s[ii + 0] * (float)x0[0] + a1s[ii + 0] * (float)x1[0];
        o0.y = a0s[ii + 1] * (float)x0[1] + a1s[ii + 1] * (float)x1[1];
        o0.z = a0s[ii + 2] * (float)x0[2] + a1s[ii + 2] * (float)x1[2];
        o0.w = a0s[ii + 3] * (float)x0[3] + a1s[ii + 3] * (float)x1[3];
        o1.x = a0s[ii + 4] * (float)x0[4] + a1s[ii + 4] * (float)x1[4];
        o1.y = a0s[ii + 5] * (float)x0[5] + a1s[ii + 5] * (float)x1[5];
        o1.z = a0s[ii + 6] * (float)x0[6] + a1s[ii + 6] * (float)x1[6];
        o1.w = a0s[ii + 7] * (float)x0[7] + a1s[ii + 7] * (float)x1[7];
        *(float4*)dst       = o0;
        *(float4*)(dst + 4) = o1;
    }
}

// ---------------------------------------------------------------------------
extern "C" void kernel_launch(void* const* d_in, const int* in_sizes, int n_in,
                              void* d_out, int out_size, void* d_ws,
                              size_t ws_size, hipStream_t stream)
{
    const float* x   = (const float*)d_in[0];
    const float* f_w = (const float*)d_in[1];
    const float* f_b = (const float*)d_in[2];
    const float* g_w = (const float*)d_in[3];
    const float* g_b = (const float*)d_in[4];
    const float* h_w = (const float*)d_in[5];
    const float* h_b = (const float*)d_in[6];
    float* out = (float*)d_out;

    _Float16* qw = (_Float16*)d_ws;
    _Float16* kw = qw + (size_t)4 * NPIX * 256;
    _Float16* vw = kw + (size_t)4 * NPIX * 256;
    _Float16* op = vw + (size_t)4 * CIN * NPIX;
    float* stats = (float*)(op + (size_t)2 * 4 * CIN * NPIX);

    proj_kernel<<<dim3(64, 16, 4), 256, 0, stream>>>(
        x, f_w, f_b, g_w, g_b, h_w, h_b, qw, kw, vw);
    attn_kernel<<<dim3(256), 512, 0, stream>>>(qw, kw, vw, op, stats);
    combine_kernel<<<dim3(64, 4), 256, 0, stream>>>(op, stats, out);
}